// Round 1
// baseline (436.724 us; speedup 1.0000x reference)
//
#include <hip/hip_runtime.h>
#include <hip/hip_bf16.h>
#include <math.h>

// Problem constants (fixed by the reference's weight shapes):
#define DM     256   // d_model
#define NHEAD  8
#define HDIM   32
#define QPAD   128   // padded query rows per (b,h)
#define NCHUNK 4     // L-chunks per (b,h) for flash parallelism

typedef __attribute__((ext_vector_type(8))) short bf16x8;  // 8 bf16 (4 VGPRs)
typedef __attribute__((ext_vector_type(4))) float f32x4;   // 4 fp32 acc

__device__ __forceinline__ short f2bf(float f) {
  // round-to-nearest-even fp32 -> bf16
  union { float f; unsigned u; } x; x.f = f;
  unsigned u = (x.u + 0x7fffu + ((x.u >> 16) & 1u)) >> 16;
  return (short)u;
}

__device__ __forceinline__ bf16x8 bzero8() {
  bf16x8 v;
#pragma unroll
  for (int j = 0; j < 8; j++) v[j] = (short)0;
  return v;
}

// ---------------------------------------------------------------------------
// Kernel 1: Q projection.  q = (query @ Wq^T + bq) * scale, bf16,
// layout Qw[b][h][row(QPAD)][hd], rows >= NQ zero-filled.
// Grid: Bn * (QPAD/8) blocks of 256 threads; each block does 8 rows x 256 dims.
// ---------------------------------------------------------------------------
__global__ __launch_bounds__(256) void q_proj_kernel(
    const float* __restrict__ query, const float* __restrict__ Wq,
    const float* __restrict__ bq, short* __restrict__ Qw, int Bn, int NQ) {
  int b  = blockIdx.x / (QPAD / 8);
  int r0 = (blockIdx.x % (QPAD / 8)) * 8;
  __shared__ __align__(16) float ql[8 * DM];
  int tid = threadIdx.x;
  for (int i = tid; i < 8 * DM; i += 256) {
    int r = r0 + (i >> 8);
    ql[i] = (r < NQ) ? query[((size_t)b * NQ + r) * DM + (i & 255)] : 0.f;
  }
  __syncthreads();
  int d = tid;
  float bias = bq[d];
  float acc[8];
#pragma unroll
  for (int qi = 0; qi < 8; qi++) acc[qi] = bias;
  const float* wrow = Wq + (size_t)d * DM;
  for (int k = 0; k < DM; k += 4) {
    float4 w = *(const float4*)(wrow + k);
#pragma unroll
    for (int qi = 0; qi < 8; qi++) {
      float4 x = *(const float4*)&ql[qi * DM + k];
      acc[qi] += x.x * w.x + x.y * w.y + x.z * w.z + x.w * w.w;
    }
  }
  const float scale = 0.17677669529663687f;  // 1/sqrt(32)
  int h = d >> 5, hd = d & 31;
#pragma unroll
  for (int qi = 0; qi < 8; qi++) {
    int r = r0 + qi;
    float v = (r < NQ) ? acc[qi] * scale : 0.f;
    Qw[(((size_t)b * NHEAD + h) * QPAD + r) * HDIM + hd] = f2bf(v);
  }
}

// ---------------------------------------------------------------------------
// Kernel 2: KV projection GEMM (bf16 MFMA, fp32 acc).
// Block: 64 tokens x 512 cols (K:256 | V:256), 4 waves x 128 cols each.
// K stored per (b,h) as (len, 32) row-major; V stored per (b,h) transposed
// (32, len) so PV B-frags are contiguous 16B loads.
// ---------------------------------------------------------------------------
__global__ __launch_bounds__(256) void kv_proj_kernel(
    const float* __restrict__ src, const float* __restrict__ Wk,
    const float* __restrict__ bk, const float* __restrict__ Wv,
    const float* __restrict__ bv, const int* __restrict__ offs,
    short* __restrict__ Kw, short* __restrict__ Vw, int T, int Bn) {
  int t0 = blockIdx.x * 64;
  int wave = threadIdx.x >> 6, lane = threadIdx.x & 63;
  int l15 = lane & 15, quad = lane >> 4;
  const float* W    = (wave < 2) ? Wk : Wv;
  const float* bias = (wave < 2) ? bk : bv;
  int colbase = (wave & 1) * 128;

  f32x4 acc[4][8];
#pragma unroll
  for (int i = 0; i < 4; i++)
#pragma unroll
    for (int j = 0; j < 8; j++) acc[i][j] = (f32x4){0.f, 0.f, 0.f, 0.f};

  for (int kk = 0; kk < DM; kk += 32) {
    bf16x8 a[4], bb[8];
#pragma unroll
    for (int mt = 0; mt < 4; mt++) {
      int tok = t0 + mt * 16 + l15;
      if (tok >= T) tok = T - 1;  // safe clamp (stores are guarded)
      const float* p = src + (size_t)tok * DM + kk + quad * 8;
      float4 x0 = *(const float4*)p, x1 = *(const float4*)(p + 4);
      bf16x8 v;
      v[0] = f2bf(x0.x); v[1] = f2bf(x0.y); v[2] = f2bf(x0.z); v[3] = f2bf(x0.w);
      v[4] = f2bf(x1.x); v[5] = f2bf(x1.y); v[6] = f2bf(x1.z); v[7] = f2bf(x1.w);
      a[mt] = v;
    }
#pragma unroll
    for (int nt = 0; nt < 8; nt++) {
      int n = colbase + nt * 16 + l15;
      const float* p = W + (size_t)n * DM + kk + quad * 8;
      float4 x0 = *(const float4*)p, x1 = *(const float4*)(p + 4);
      bf16x8 v;
      v[0] = f2bf(x0.x); v[1] = f2bf(x0.y); v[2] = f2bf(x0.z); v[3] = f2bf(x0.w);
      v[4] = f2bf(x1.x); v[5] = f2bf(x1.y); v[6] = f2bf(x1.z); v[7] = f2bf(x1.w);
      bb[nt] = v;
    }
#pragma unroll
    for (int mt = 0; mt < 4; mt++)
#pragma unroll
      for (int nt = 0; nt < 8; nt++)
        acc[mt][nt] = __builtin_amdgcn_mfma_f32_16x16x32_bf16(
            a[mt], bb[nt], acc[mt][nt], 0, 0, 0);
  }

  // Epilogue: +bias, convert, scatter into per-(b,h) layouts.
  int bcur = 0;
#pragma unroll
  for (int mt = 0; mt < 4; mt++) {
#pragma unroll
    for (int r = 0; r < 4; r++) {
      int tok = t0 + mt * 16 + quad * 4 + r;
      if (tok >= T) continue;
      while (bcur + 1 < Bn && offs[bcur + 1] <= tok) bcur++;
      int off = offs[bcur], len = offs[bcur + 1] - off;
      int l = tok - off;
      size_t hbase0 = (size_t)off * DM;  // elements consumed by prior batches
#pragma unroll
      for (int nt = 0; nt < 8; nt++) {
        int n = colbase + nt * 16 + l15;
        float v = acc[mt][nt][r] + bias[n];
        int h = n >> 5, hd = n & 31;
        size_t base = hbase0 + (size_t)h * len * HDIM;
        if (wave < 2)
          Kw[base + (size_t)l * HDIM + hd] = f2bf(v);   // K: (l, hd)
        else
          Vw[base + (size_t)hd * len + l] = f2bf(v);    // V^T: (hd, l)
      }
    }
  }
}

// ---------------------------------------------------------------------------
// Kernel 3: flash attention per (b, h, chunk). 4 waves x 32 query rows.
// Writes unnormalized O (QPAD x 32 fp32) + per-row (m, l).
// ---------------------------------------------------------------------------
__global__ __launch_bounds__(256) void attn_kernel(
    const short* __restrict__ Qw, const short* __restrict__ Kw,
    const short* __restrict__ Vw, const int* __restrict__ offs,
    float* __restrict__ Op, float* __restrict__ Ml, int Bn) {
  int c  = blockIdx.x % NCHUNK;
  int bh = blockIdx.x / NCHUNK;
  int h = bh % NHEAD, b = bh / NHEAD;
  int wave = threadIdx.x >> 6, lane = threadIdx.x & 63;
  int l15 = lane & 15, quad = lane >> 4;

  int off = offs[b], len = offs[b + 1] - off;
  int cl = ((len + NCHUNK * 32 - 1) / (NCHUNK * 32)) * 32;  // ceil to x32
  int kstart = c * cl;
  int kend   = min(kstart + cl, len);

  const short* Kh = Kw + (size_t)off * DM + (size_t)h * len * HDIM;
  const short* Vh = Vw + (size_t)off * DM + (size_t)h * len * HDIM;

  bf16x8 aq[2];
#pragma unroll
  for (int mt = 0; mt < 2; mt++) {
    int row = wave * 32 + mt * 16 + l15;
    aq[mt] = *(const bf16x8*)(Qw + (((size_t)b * NHEAD + h) * QPAD + row) * HDIM +
                              quad * 8);
  }

  f32x4 o[2][2];
#pragma unroll
  for (int i = 0; i < 2; i++)
#pragma unroll
    for (int j = 0; j < 2; j++) o[i][j] = (f32x4){0.f, 0.f, 0.f, 0.f};
  float mrun[2][4], lrun[2][4];
#pragma unroll
  for (int i = 0; i < 2; i++)
#pragma unroll
    for (int r = 0; r < 4; r++) { mrun[i][r] = -1e30f; lrun[i][r] = 0.f; }

  // wave-private P transpose buffer (C-layout -> A-layout round trip)
  __shared__ __align__(16) short plds[4][32][40];  // +8 pad breaks conflicts

  for (int kb = kstart; kb < kend; kb += 32) {
    bool valid[2]; int key[2];
    bf16x8 bk_[2];
#pragma unroll
    for (int nt = 0; nt < 2; nt++) {
      key[nt] = kb + nt * 16 + l15;
      valid[nt] = key[nt] < kend;
      bk_[nt] = valid[nt] ? *(const bf16x8*)(Kh + (size_t)key[nt] * HDIM + quad * 8)
                          : bzero8();
    }
    f32x4 zero = {0.f, 0.f, 0.f, 0.f};
    f32x4 s[2][2];
#pragma unroll
    for (int mt = 0; mt < 2; mt++)
#pragma unroll
      for (int nt = 0; nt < 2; nt++)
        s[mt][nt] = __builtin_amdgcn_mfma_f32_16x16x32_bf16(aq[mt], bk_[nt], zero,
                                                            0, 0, 0);
    // online softmax: rows live in quad*4+r; cols across the 16-lane group
#pragma unroll
    for (int mt = 0; mt < 2; mt++) {
#pragma unroll
      for (int r = 0; r < 4; r++) {
        float v0 = valid[0] ? s[mt][0][r] : -1e30f;
        float v1 = valid[1] ? s[mt][1][r] : -1e30f;
        float t = fmaxf(v0, v1);
        t = fmaxf(t, __shfl_xor(t, 1, 16));
        t = fmaxf(t, __shfl_xor(t, 2, 16));
        t = fmaxf(t, __shfl_xor(t, 4, 16));
        t = fmaxf(t, __shfl_xor(t, 8, 16));
        float mn = fmaxf(mrun[mt][r], t);
        float al = __expf(mrun[mt][r] - mn);
        float p0 = valid[0] ? __expf(v0 - mn) : 0.f;
        float p1 = valid[1] ? __expf(v1 - mn) : 0.f;
        float rs = p0 + p1;
        rs += __shfl_xor(rs, 1, 16);
        rs += __shfl_xor(rs, 2, 16);
        rs += __shfl_xor(rs, 4, 16);
        rs += __shfl_xor(rs, 8, 16);
        lrun[mt][r] = al * lrun[mt][r] + rs;
        mrun[mt][r] = mn;
        o[mt][0][r] *= al;
        o[mt][1][r] *= al;
        plds[wave][mt * 16 + quad * 4 + r][l15]      = f2bf(p0);
        plds[wave][mt * 16 + quad * 4 + r][16 + l15] = f2bf(p1);
      }
    }
    // P: C-layout -> A-layout (wave-private LDS; program order + lgkmcnt)
    bf16x8 pa[2];
#pragma unroll
    for (int mt = 0; mt < 2; mt++)
      pa[mt] = *(const bf16x8*)&plds[wave][mt * 16 + l15][quad * 8];
    // V^T B-frags: contiguous 16B
    bf16x8 bv_[2];
#pragma unroll
    for (int ht = 0; ht < 2; ht++) {
      int hd = ht * 16 + l15;
      int k0 = kb + quad * 8;
      const short* p = Vh + (size_t)hd * len + k0;
      if (k0 + 7 < len) {
        bv_[ht] = *(const bf16x8*)p;
      } else {
        bf16x8 v;
#pragma unroll
        for (int j = 0; j < 8; j++) v[j] = (k0 + j < len) ? p[j] : (short)0;
        bv_[ht] = v;
      }
    }
#pragma unroll
    for (int mt = 0; mt < 2; mt++)
#pragma unroll
      for (int ht = 0; ht < 2; ht++)
        o[mt][ht] = __builtin_amdgcn_mfma_f32_16x16x32_bf16(pa[mt], bv_[ht],
                                                            o[mt][ht], 0, 0, 0);
  }

  // store partials
#pragma unroll
  for (int mt = 0; mt < 2; mt++) {
#pragma unroll
    for (int r = 0; r < 4; r++) {
      int row = wave * 32 + mt * 16 + quad * 4 + r;
      size_t base = (((size_t)c * Bn + b) * NHEAD + h) * QPAD + row;
#pragma unroll
      for (int ht = 0; ht < 2; ht++)
        Op[base * HDIM + ht * 16 + l15] = o[mt][ht][r];
      if (l15 == 0) {
        Ml[base * 2]     = mrun[mt][r];
        Ml[base * 2 + 1] = lrun[mt][r];
      }
    }
  }
}

// ---------------------------------------------------------------------------
// Kernel 4: chunk combine + out-projection + residual.
// Block: 8 queries of one batch; thread d = output dim.
// ---------------------------------------------------------------------------
__global__ __launch_bounds__(256) void combine_kernel(
    const float* __restrict__ Op, const float* __restrict__ Ml,
    const float* __restrict__ query, const float* __restrict__ Wo,
    const float* __restrict__ bo, float* __restrict__ out, int Bn, int NQ) {
  int bpb = (NQ + 7) / 8;
  int b  = blockIdx.x / bpb;
  int q0 = (blockIdx.x % bpb) * 8;
  __shared__ __align__(16) float ctx[8 * DM];
  int d = threadIdx.x;
  int h = d >> 5, hd = d & 31;
#pragma unroll
  for (int qi = 0; qi < 8; qi++) {
    int q = q0 + qi;
    float val = 0.f;
    if (q < NQ) {
      float mc[NCHUNK], lc[NCHUNK], M = -1e30f;
#pragma unroll
      for (int c = 0; c < NCHUNK; c++) {
        size_t base = (((size_t)c * Bn + b) * NHEAD + h) * QPAD + q;
        mc[c] = Ml[base * 2];
        lc[c] = Ml[base * 2 + 1];
        M = fmaxf(M, mc[c]);
      }
      float L = 0.f, acc = 0.f;
#pragma unroll
      for (int c = 0; c < NCHUNK; c++) {
        size_t base = (((size_t)c * Bn + b) * NHEAD + h) * QPAD + q;
        float w = __expf(mc[c] - M);
        L += lc[c] * w;
        acc += w * Op[base * HDIM + hd];
      }
      val = (L > 0.f) ? acc / L : 0.f;
    }
    ctx[qi * DM + d] = val;
  }
  __syncthreads();
  const float* wrow = Wo + (size_t)d * DM;
  float acc[8];
  float bias = bo[d];
#pragma unroll
  for (int qi = 0; qi < 8; qi++) acc[qi] = bias;
  for (int k = 0; k < DM; k += 4) {
    float4 w = *(const float4*)(wrow + k);
#pragma unroll
    for (int qi = 0; qi < 8; qi++) {
      float4 x = *(const float4*)&ctx[qi * DM + k];
      acc[qi] += x.x * w.x + x.y * w.y + x.z * w.z + x.w * w.w;
    }
  }
#pragma unroll
  for (int qi = 0; qi < 8; qi++) {
    int q = q0 + qi;
    if (q < NQ)
      out[((size_t)b * NQ + q) * DM + d] =
          acc[qi] + query[((size_t)b * NQ + q) * DM + d];
  }
}

// ---------------------------------------------------------------------------
extern "C" void kernel_launch(void* const* d_in, const int* in_sizes, int n_in,
                              void* d_out, int out_size, void* d_ws,
                              size_t ws_size, hipStream_t stream) {
  const float* src   = (const float*)d_in[0];
  const float* query = (const float*)d_in[1];
  const int*   offs  = (const int*)d_in[2];
  const float* Wq = (const float*)d_in[3];
  const float* bq = (const float*)d_in[4];
  const float* Wk = (const float*)d_in[5];
  const float* bk = (const float*)d_in[6];
  const float* Wv = (const float*)d_in[7];
  const float* bv = (const float*)d_in[8];
  const float* Wo = (const float*)d_in[9];
  const float* bo = (const float*)d_in[10];
  float* out = (float*)d_out;

  int T  = in_sizes[0] / DM;        // total tokens (65536)
  int Bn = in_sizes[2] - 1;         // batch size (16)
  int NQ = in_sizes[1] / (Bn * DM); // queries per sample (100)

  // Workspace layout (needs ~78 MB):
  char* w = (char*)d_ws;
  size_t qsz = (size_t)Bn * NHEAD * QPAD * HDIM * 2;            // 1 MB
  size_t ksz = (size_t)T * DM * 2;                              // 33.5 MB
  size_t osz = (size_t)NCHUNK * Bn * NHEAD * QPAD * HDIM * 4;   // 8.4 MB
  short* Qw = (short*)w;
  short* Kw = (short*)(w + qsz);
  short* Vw = (short*)(w + qsz + ksz);
  float* Op = (float*)(w + qsz + 2 * ksz);
  float* Mlp = (float*)(w + qsz + 2 * ksz + osz);

  q_proj_kernel<<<Bn * (QPAD / 8), 256, 0, stream>>>(query, Wq, bq, Qw, Bn, NQ);
  kv_proj_kernel<<<(T + 63) / 64, 256, 0, stream>>>(src, Wk, bk, Wv, bv, offs,
                                                    Kw, Vw, T, Bn);
  attn_kernel<<<Bn * NHEAD * NCHUNK, 256, 0, stream>>>(Qw, Kw, Vw, offs, Op,
                                                       Mlp, Bn);
  combine_kernel<<<Bn * ((NQ + 7) / 8), 256, 0, stream>>>(Op, Mlp, query, Wo,
                                                          bo, out, Bn, NQ);
}

// Round 2
// 332.211 us; speedup vs baseline: 1.3146x; 1.3146x over previous
//
#include <hip/hip_runtime.h>
#include <hip/hip_bf16.h>
#include <math.h>

// Problem constants (fixed by the reference's weight shapes):
#define DM     256   // d_model
#define NHEAD  8
#define HDIM   32
#define QPAD   128   // padded query rows per (b,h)
#define NCHUNK 4     // L-chunks per (b,h) for flash parallelism
#define BM     128   // kv_gemm M-tile (tokens)
#define BN     128   // kv_gemm N-tile (output cols)
#define BK     32    // kv_gemm K-step

typedef __attribute__((ext_vector_type(8))) short bf16x8;  // 8 bf16 (4 VGPRs)
typedef __attribute__((ext_vector_type(4))) float f32x4;   // 4 fp32 acc

__device__ __forceinline__ short f2bf(float f) {
  // round-to-nearest-even fp32 -> bf16
  union { float f; unsigned u; } x; x.f = f;
  unsigned u = (x.u + 0x7fffu + ((x.u >> 16) & 1u)) >> 16;
  return (short)u;
}

__device__ __forceinline__ bf16x8 bzero8() {
  bf16x8 v;
#pragma unroll
  for (int j = 0; j < 8; j++) v[j] = (short)0;
  return v;
}

__device__ __forceinline__ void gl2lds16(const void* g, void* l) {
  __builtin_amdgcn_global_load_lds(
      (const __attribute__((address_space(1))) unsigned*)g,
      (__attribute__((address_space(3))) unsigned*)l, 16, 0, 0);
}

__device__ __forceinline__ bf16x8 cvt8(const float* p) {
  float4 x0 = *(const float4*)p, x1 = *(const float4*)(p + 4);
  bf16x8 v;
  v[0] = f2bf(x0.x); v[1] = f2bf(x0.y); v[2] = f2bf(x0.z); v[3] = f2bf(x0.w);
  v[4] = f2bf(x1.x); v[5] = f2bf(x1.y); v[6] = f2bf(x1.z); v[7] = f2bf(x1.w);
  return v;
}

// ---------------------------------------------------------------------------
// Kernel 0: weight convert.  Wkv[n][k] bf16; n<256 -> Wk row n, else Wv.
// ---------------------------------------------------------------------------
__global__ __launch_bounds__(256) void wconv_kernel(
    const float* __restrict__ Wk, const float* __restrict__ Wv,
    short* __restrict__ Wkv) {
  int idx = blockIdx.x * 256 + threadIdx.x;  // 16384 threads, 8 elems each
  int e0 = idx * 8;
  const float* p = (e0 < DM * DM) ? (Wk + e0) : (Wv + (e0 - DM * DM));
  *(bf16x8*)(Wkv + e0) = cvt8(p);
}

// ---------------------------------------------------------------------------
// Kernel 1: Q projection.  q = (query @ Wq^T + bq) * scale, bf16,
// layout Qw[b][h][row(QPAD)][hd], rows >= NQ zero-filled.
// ---------------------------------------------------------------------------
__global__ __launch_bounds__(256) void q_proj_kernel(
    const float* __restrict__ query, const float* __restrict__ Wq,
    const float* __restrict__ bq, short* __restrict__ Qw, int Bn, int NQ) {
  int b  = blockIdx.x / (QPAD / 8);
  int r0 = (blockIdx.x % (QPAD / 8)) * 8;
  __shared__ __align__(16) float ql[8 * DM];
  int tid = threadIdx.x;
  for (int i = tid; i < 8 * DM; i += 256) {
    int r = r0 + (i >> 8);
    ql[i] = (r < NQ) ? query[((size_t)b * NQ + r) * DM + (i & 255)] : 0.f;
  }
  __syncthreads();
  int d = tid;
  float bias = bq[d];
  float acc[8];
#pragma unroll
  for (int qi = 0; qi < 8; qi++) acc[qi] = bias;
  const float* wrow = Wq + (size_t)d * DM;
  for (int k = 0; k < DM; k += 4) {
    float4 w = *(const float4*)(wrow + k);
#pragma unroll
    for (int qi = 0; qi < 8; qi++) {
      float4 x = *(const float4*)&ql[qi * DM + k];
      acc[qi] += x.x * w.x + x.y * w.y + x.z * w.z + x.w * w.w;
    }
  }
  const float scale = 0.17677669529663687f;  // 1/sqrt(32)
  int h = d >> 5, hd = d & 31;
#pragma unroll
  for (int qi = 0; qi < 8; qi++) {
    int r = r0 + qi;
    float v = (r < NQ) ? acc[qi] * scale : 0.f;
    Qw[(((size_t)b * NHEAD + h) * QPAD + r) * HDIM + hd] = f2bf(v);
  }
}

// ---------------------------------------------------------------------------
// Kernel 2: KV projection GEMM, LDS-staged 128x128 tile, 4 waves (2x2),
// each wave 64x64 via 4x4 16x16x32 MFMAs. A: src fp32 -> bf16 fused at
// staging (coalesced float4 loads, ds_write_b128). B: pre-converted bf16
// weights via global_load_lds width=16.
// Grid n-major: idx = n*Mtiles + m, so the 4 blocks sharing an A-tile get
// idx%8 == m%8 (same XCD -> L2 reuse of A).
// ---------------------------------------------------------------------------
__global__ __launch_bounds__(256) void kv_gemm_kernel(
    const float* __restrict__ src, const short* __restrict__ Wkv,
    const float* __restrict__ bk, const float* __restrict__ bv,
    const int* __restrict__ offs, short* __restrict__ Kw,
    short* __restrict__ Vw, int T, int Bn, int Mtiles) {
  int ntile = blockIdx.x / Mtiles;
  int mtile = blockIdx.x % Mtiles;
  int t0 = mtile * BM;
  int n0 = ntile * BN;
  bool isK = (n0 < DM);
  int n0rel = n0 & (DM - 1);  // 0 or 128 within the K- or V-projection
  const float* bias = isK ? bk : bv;

  int tid = threadIdx.x;
  int wave = tid >> 6, lane = tid & 63;
  int l15 = lane & 15, quad = lane >> 4;
  int wm = wave >> 1, wn = wave & 1;

  __shared__ __align__(16) short As[BM][BK + 8];  // padded (stride 80B)
  __shared__ __align__(16) short Bs[BN * BK];     // unpadded (global_load_lds)

  f32x4 acc[4][4];
#pragma unroll
  for (int i = 0; i < 4; i++)
#pragma unroll
    for (int j = 0; j < 4; j++) acc[i][j] = (f32x4){0.f, 0.f, 0.f, 0.f};

  for (int kk = 0; kk < DM; kk += BK) {
    __syncthreads();  // protect LDS from previous iteration's readers
    // ---- stage A: 128 rows x 32 k, fp32 -> bf16 ----
#pragma unroll
    for (int s2 = 0; s2 < 2; s2++) {
      int s = tid + s2 * 256;
      int row = s >> 2, ch = s & 3;
      int tok = t0 + row;
      if (tok >= T) tok = T - 1;  // epilogue guards real stores
      *(bf16x8*)&As[row][ch * 8] = cvt8(src + (size_t)tok * DM + kk + ch * 8);
    }
    // ---- stage B: 128 cols x 32 k bf16 via global_load_lds ----
    {
      int colw = lane >> 2, ko = (lane & 3) * 8;
#pragma unroll
      for (int j = 0; j < 2; j++) {
        int cb = wave * 32 + j * 16;  // wave-uniform LDS base
        const short* g = Wkv + (size_t)(n0 + cb + colw) * DM + kk + ko;
        gl2lds16(g, &Bs[cb * BK]);
      }
    }
    __syncthreads();
    // ---- fragments + MFMA ----
    bf16x8 af[4], bf_[4];
#pragma unroll
    for (int mt = 0; mt < 4; mt++)
      af[mt] = *(const bf16x8*)&As[wm * 64 + mt * 16 + l15][quad * 8];
#pragma unroll
    for (int nt = 0; nt < 4; nt++)
      bf_[nt] = *(const bf16x8*)&Bs[(wn * 64 + nt * 16 + l15) * BK + quad * 8];
#pragma unroll
    for (int mt = 0; mt < 4; mt++)
#pragma unroll
      for (int nt = 0; nt < 4; nt++)
        acc[mt][nt] = __builtin_amdgcn_mfma_f32_16x16x32_bf16(
            af[mt], bf_[nt], acc[mt][nt], 0, 0, 0);
  }

  // ---- epilogue: +bias, bf16, scatter to per-(b,h) K (l,hd) / V^T (hd,l) ----
  float bias4[4];
  int hh[4], hd4[4];
#pragma unroll
  for (int nt = 0; nt < 4; nt++) {
    int nr = n0rel + wn * 64 + nt * 16 + l15;
    bias4[nt] = bias[nr];
    hh[nt] = nr >> 5;
    hd4[nt] = nr & 31;
  }
  int bcur = 0;
#pragma unroll
  for (int mt = 0; mt < 4; mt++) {
#pragma unroll
    for (int r = 0; r < 4; r++) {
      int tok = t0 + wm * 64 + mt * 16 + quad * 4 + r;
      if (tok >= T) continue;
      while (bcur + 1 < Bn && offs[bcur + 1] <= tok) bcur++;
      int off = offs[bcur], len = offs[bcur + 1] - off;
      int l = tok - off;
      size_t hbase0 = (size_t)off * DM;
#pragma unroll
      for (int nt = 0; nt < 4; nt++) {
        float v = acc[mt][nt][r] + bias4[nt];
        size_t base = hbase0 + (size_t)hh[nt] * len * HDIM;
        if (isK)
          Kw[base + (size_t)l * HDIM + hd4[nt]] = f2bf(v);  // K: (l, hd)
        else
          Vw[base + (size_t)hd4[nt] * len + l] = f2bf(v);   // V^T: (hd, l)
      }
    }
  }
}

// ---------------------------------------------------------------------------
// Kernel 3: flash attention per (b, h, chunk). 4 waves x 32 query rows.
// Writes unnormalized O (QPAD x 32 fp32) + per-row (m, l).
// ---------------------------------------------------------------------------
__global__ __launch_bounds__(256) void attn_kernel(
    const short* __restrict__ Qw, const short* __restrict__ Kw,
    const short* __restrict__ Vw, const int* __restrict__ offs,
    float* __restrict__ Op, float* __restrict__ Ml, int Bn) {
  int c  = blockIdx.x % NCHUNK;
  int bh = blockIdx.x / NCHUNK;
  int h = bh % NHEAD, b = bh / NHEAD;
  int wave = threadIdx.x >> 6, lane = threadIdx.x & 63;
  int l15 = lane & 15, quad = lane >> 4;

  int off = offs[b], len = offs[b + 1] - off;
  int cl = ((len + NCHUNK * 32 - 1) / (NCHUNK * 32)) * 32;  // ceil to x32
  int kstart = c * cl;
  int kend   = min(kstart + cl, len);

  const short* Kh = Kw + (size_t)off * DM + (size_t)h * len * HDIM;
  const short* Vh = Vw + (size_t)off * DM + (size_t)h * len * HDIM;

  bf16x8 aq[2];
#pragma unroll
  for (int mt = 0; mt < 2; mt++) {
    int row = wave * 32 + mt * 16 + l15;
    aq[mt] = *(const bf16x8*)(Qw + (((size_t)b * NHEAD + h) * QPAD + row) * HDIM +
                              quad * 8);
  }

  f32x4 o[2][2];
#pragma unroll
  for (int i = 0; i < 2; i++)
#pragma unroll
    for (int j = 0; j < 2; j++) o[i][j] = (f32x4){0.f, 0.f, 0.f, 0.f};
  float mrun[2][4], lrun[2][4];
#pragma unroll
  for (int i = 0; i < 2; i++)
#pragma unroll
    for (int r = 0; r < 4; r++) { mrun[i][r] = -1e30f; lrun[i][r] = 0.f; }

  // wave-private P transpose buffer (C-layout -> A-layout round trip)
  __shared__ __align__(16) short plds[4][32][40];  // +8 pad breaks conflicts

  for (int kb = kstart; kb < kend; kb += 32) {
    bool valid[2]; int key[2];
    bf16x8 bk_[2];
#pragma unroll
    for (int nt = 0; nt < 2; nt++) {
      key[nt] = kb + nt * 16 + l15;
      valid[nt] = key[nt] < kend;
      bk_[nt] = valid[nt] ? *(const bf16x8*)(Kh + (size_t)key[nt] * HDIM + quad * 8)
                          : bzero8();
    }
    f32x4 zero = {0.f, 0.f, 0.f, 0.f};
    f32x4 s[2][2];
#pragma unroll
    for (int mt = 0; mt < 2; mt++)
#pragma unroll
      for (int nt = 0; nt < 2; nt++)
        s[mt][nt] = __builtin_amdgcn_mfma_f32_16x16x32_bf16(aq[mt], bk_[nt], zero,
                                                            0, 0, 0);
    // online softmax: rows live in quad*4+r; cols across the 16-lane group
#pragma unroll
    for (int mt = 0; mt < 2; mt++) {
#pragma unroll
      for (int r = 0; r < 4; r++) {
        float v0 = valid[0] ? s[mt][0][r] : -1e30f;
        float v1 = valid[1] ? s[mt][1][r] : -1e30f;
        float t = fmaxf(v0, v1);
        t = fmaxf(t, __shfl_xor(t, 1, 16));
        t = fmaxf(t, __shfl_xor(t, 2, 16));
        t = fmaxf(t, __shfl_xor(t, 4, 16));
        t = fmaxf(t, __shfl_xor(t, 8, 16));
        float mn = fmaxf(mrun[mt][r], t);
        float al = __expf(mrun[mt][r] - mn);
        float p0 = valid[0] ? __expf(v0 - mn) : 0.f;
        float p1 = valid[1] ? __expf(v1 - mn) : 0.f;
        float rs = p0 + p1;
        rs += __shfl_xor(rs, 1, 16);
        rs += __shfl_xor(rs, 2, 16);
        rs += __shfl_xor(rs, 4, 16);
        rs += __shfl_xor(rs, 8, 16);
        lrun[mt][r] = al * lrun[mt][r] + rs;
        mrun[mt][r] = mn;
        o[mt][0][r] *= al;
        o[mt][1][r] *= al;
        plds[wave][mt * 16 + quad * 4 + r][l15]      = f2bf(p0);
        plds[wave][mt * 16 + quad * 4 + r][16 + l15] = f2bf(p1);
      }
    }
    // P: C-layout -> A-layout (wave-private LDS; program order + lgkmcnt)
    bf16x8 pa[2];
#pragma unroll
    for (int mt = 0; mt < 2; mt++)
      pa[mt] = *(const bf16x8*)&plds[wave][mt * 16 + l15][quad * 8];
    // V^T B-frags: contiguous 16B
    bf16x8 bv_[2];
#pragma unroll
    for (int ht = 0; ht < 2; ht++) {
      int hd = ht * 16 + l15;
      int k0 = kb + quad * 8;
      const short* p = Vh + (size_t)hd * len + k0;
      if (k0 + 7 < len) {
        bv_[ht] = *(const bf16x8*)p;
      } else {
        bf16x8 v;
#pragma unroll
        for (int j = 0; j < 8; j++) v[j] = (k0 + j < len) ? p[j] : (short)0;
        bv_[ht] = v;
      }
    }
#pragma unroll
    for (int mt = 0; mt < 2; mt++)
#pragma unroll
      for (int ht = 0; ht < 2; ht++)
        o[mt][ht] = __builtin_amdgcn_mfma_f32_16x16x32_bf16(pa[mt], bv_[ht],
                                                            o[mt][ht], 0, 0, 0);
  }

  // store partials
#pragma unroll
  for (int mt = 0; mt < 2; mt++) {
#pragma unroll
    for (int r = 0; r < 4; r++) {
      int row = wave * 32 + mt * 16 + quad * 4 + r;
      size_t base = (((size_t)c * Bn + b) * NHEAD + h) * QPAD + row;
#pragma unroll
      for (int ht = 0; ht < 2; ht++)
        Op[base * HDIM + ht * 16 + l15] = o[mt][ht][r];
      if (l15 == 0) {
        Ml[base * 2]     = mrun[mt][r];
        Ml[base * 2 + 1] = lrun[mt][r];
      }
    }
  }
}

// ---------------------------------------------------------------------------
// Kernel 4: chunk combine + out-projection + residual.
// ---------------------------------------------------------------------------
__global__ __launch_bounds__(256) void combine_kernel(
    const float* __restrict__ Op, const float* __restrict__ Ml,
    const float* __restrict__ query, const float* __restrict__ Wo,
    const float* __restrict__ bo, float* __restrict__ out, int Bn, int NQ) {
  int bpb = (NQ + 7) / 8;
  int b  = blockIdx.x / bpb;
  int q0 = (blockIdx.x % bpb) * 8;
  __shared__ __align__(16) float ctx[8 * DM];
  int d = threadIdx.x;
  int h = d >> 5, hd = d & 31;
#pragma unroll
  for (int qi = 0; qi < 8; qi++) {
    int q = q0 + qi;
    float val = 0.f;
    if (q < NQ) {
      float mc[NCHUNK], lc[NCHUNK], M = -1e30f;
#pragma unroll
      for (int c = 0; c < NCHUNK; c++) {
        size_t base = (((size_t)c * Bn + b) * NHEAD + h) * QPAD + q;
        mc[c] = Ml[base * 2];
        lc[c] = Ml[base * 2 + 1];
        M = fmaxf(M, mc[c]);
      }
      float L = 0.f, acc = 0.f;
#pragma unroll
      for (int c = 0; c < NCHUNK; c++) {
        size_t base = (((size_t)c * Bn + b) * NHEAD + h) * QPAD + q;
        float w = __expf(mc[c] - M);
        L += lc[c] * w;
        acc += w * Op[base * HDIM + hd];
      }
      val = (L > 0.f) ? acc / L : 0.f;
    }
    ctx[qi * DM + d] = val;
  }
  __syncthreads();
  const float* wrow = Wo + (size_t)d * DM;
  float acc[8];
  float bias = bo[d];
#pragma unroll
  for (int qi = 0; qi < 8; qi++) acc[qi] = bias;
  for (int k = 0; k < DM; k += 4) {
    float4 w = *(const float4*)(wrow + k);
#pragma unroll
    for (int qi = 0; qi < 8; qi++) {
      float4 x = *(const float4*)&ctx[qi * DM + k];
      acc[qi] += x.x * w.x + x.y * w.y + x.z * w.z + x.w * w.w;
    }
  }
#pragma unroll
  for (int qi = 0; qi < 8; qi++) {
    int q = q0 + qi;
    if (q < NQ)
      out[((size_t)b * NQ + q) * DM + d] =
          acc[qi] + query[((size_t)b * NQ + q) * DM + d];
  }
}

// ---------------------------------------------------------------------------
extern "C" void kernel_launch(void* const* d_in, const int* in_sizes, int n_in,
                              void* d_out, int out_size, void* d_ws,
                              size_t ws_size, hipStream_t stream) {
  const float* src   = (const float*)d_in[0];
  const float* query = (const float*)d_in[1];
  const int*   offs  = (const int*)d_in[2];
  const float* Wq = (const float*)d_in[3];
  const float* bq = (const float*)d_in[4];
  const float* Wk = (const float*)d_in[5];
  const float* bk = (const float*)d_in[6];
  const float* Wv = (const float*)d_in[7];
  const float* bv = (const float*)d_in[8];
  const float* Wo = (const float*)d_in[9];
  const float* bo = (const float*)d_in[10];
  float* out = (float*)d_out;

  int T  = in_sizes[0] / DM;        // total tokens (65536)
  int Bn = in_sizes[2] - 1;         // batch size (16)
  int NQ = in_sizes[1] / (Bn * DM); // queries per sample (100)

  // Workspace layout (~78 MB):
  char* w = (char*)d_ws;
  size_t qsz = (size_t)Bn * NHEAD * QPAD * HDIM * 2;            // 1 MB
  size_t ksz = (size_t)T * DM * 2;                              // 33.5 MB
  size_t osz = (size_t)NCHUNK * Bn * NHEAD * QPAD * HDIM * 4;   // 8.4 MB
  size_t msz = (size_t)NCHUNK * Bn * NHEAD * QPAD * 2 * 4;      // 0.5 MB
  short* Qw  = (short*)w;
  short* Kw  = (short*)(w + qsz);
  short* Vw  = (short*)(w + qsz + ksz);
  float* Op  = (float*)(w + qsz + 2 * ksz);
  float* Mlp = (float*)(w + qsz + 2 * ksz + osz);
  short* Wkv = (short*)(w + qsz + 2 * ksz + osz + msz);         // 0.26 MB

  int Mtiles = (T + BM - 1) / BM;

  wconv_kernel<<<(2 * DM * DM) / (256 * 8), 256, 0, stream>>>(Wk, Wv, Wkv);
  q_proj_kernel<<<Bn * (QPAD / 8), 256, 0, stream>>>(query, Wq, bq, Qw, Bn, NQ);
  kv_gemm_kernel<<<Mtiles * (2 * DM / BN), 256, 0, stream>>>(
      src, Wkv, bk, bv, offs, Kw, Vw, T, Bn, Mtiles);
  attn_kernel<<<Bn * NHEAD * NCHUNK, 256, 0, stream>>>(Qw, Kw, Vw, offs, Op,
                                                       Mlp, Bn);
  combine_kernel<<<Bn * ((NQ + 7) / 8), 256, 0, stream>>>(Op, Mlp, query, Wo,
                                                          bo, out, Bn, NQ);
}

// Round 3
// 271.713 us; speedup vs baseline: 1.6073x; 1.2227x over previous
//
#include <hip/hip_runtime.h>
#include <hip/hip_bf16.h>
#include <math.h>

// Problem constants (fixed by the reference's weight shapes):
#define DM     256   // d_model
#define NHEAD  8
#define HDIM   32
#define QPAD   112   // padded query rows per (b,h): 7 waves x 16 rows
#define NCHUNK 8     // L-chunks per (b,h) for flash parallelism
#define BM     128   // kv_gemm M-tile (tokens)
#define BN     128   // kv_gemm N-tile (output cols)
#define BK     32    // kv_gemm K-step

typedef __attribute__((ext_vector_type(8))) short bf16x8;  // 8 bf16 (4 VGPRs)
typedef __attribute__((ext_vector_type(4))) short bf16x4;  // 8B packed store
typedef __attribute__((ext_vector_type(4))) float f32x4;   // 4 fp32 acc

__device__ __forceinline__ short f2bf(float f) {
  union { float f; unsigned u; } x; x.f = f;
  unsigned u = (x.u + 0x7fffu + ((x.u >> 16) & 1u)) >> 16;
  return (short)u;
}
__device__ __forceinline__ float bf2f(short s) {
  union { unsigned u; float f; } x; x.u = ((unsigned)(unsigned short)s) << 16;
  return x.f;
}
__device__ __forceinline__ bf16x8 bzero8() {
  bf16x8 v;
#pragma unroll
  for (int j = 0; j < 8; j++) v[j] = (short)0;
  return v;
}
__device__ __forceinline__ void gl2lds16(const void* g, void* l) {
  __builtin_amdgcn_global_load_lds(
      (const __attribute__((address_space(1))) unsigned*)g,
      (__attribute__((address_space(3))) unsigned*)l, 16, 0, 0);
}
__device__ __forceinline__ bf16x8 cvt8(const float* p) {
  float4 x0 = *(const float4*)p, x1 = *(const float4*)(p + 4);
  bf16x8 v;
  v[0] = f2bf(x0.x); v[1] = f2bf(x0.y); v[2] = f2bf(x0.z); v[3] = f2bf(x0.w);
  v[4] = f2bf(x1.x); v[5] = f2bf(x1.y); v[6] = f2bf(x1.z); v[7] = f2bf(x1.w);
  return v;
}

// ---------------------------------------------------------------------------
// Kernel 0: weight convert.  Wkv[n][k] bf16; n<256 -> Wk row n, else Wv.
// ---------------------------------------------------------------------------
__global__ __launch_bounds__(256) void wconv_kernel(
    const float* __restrict__ Wk, const float* __restrict__ Wv,
    short* __restrict__ Wkv) {
  int idx = blockIdx.x * 256 + threadIdx.x;
  int e0 = idx * 8;
  const float* p = (e0 < DM * DM) ? (Wk + e0) : (Wv + (e0 - DM * DM));
  *(bf16x8*)(Wkv + e0) = cvt8(p);
}

// ---------------------------------------------------------------------------
// Kernel 1: Q projection.  q = (query @ Wq^T + bq) * scale, bf16,
// layout Qw[b][h][row(QPAD)][hd], rows >= NQ zero-filled.
// ---------------------------------------------------------------------------
__global__ __launch_bounds__(256) void q_proj_kernel(
    const float* __restrict__ query, const float* __restrict__ Wq,
    const float* __restrict__ bq, short* __restrict__ Qw, int Bn, int NQ) {
  int b  = blockIdx.x / (QPAD / 8);
  int r0 = (blockIdx.x % (QPAD / 8)) * 8;
  __shared__ __align__(16) float ql[8 * DM];
  int tid = threadIdx.x;
  for (int i = tid; i < 8 * DM; i += 256) {
    int r = r0 + (i >> 8);
    ql[i] = (r < NQ) ? query[((size_t)b * NQ + r) * DM + (i & 255)] : 0.f;
  }
  __syncthreads();
  int d = tid;
  float bias = bq[d];
  float acc[8];
#pragma unroll
  for (int qi = 0; qi < 8; qi++) acc[qi] = bias;
  const float* wrow = Wq + (size_t)d * DM;
  for (int k = 0; k < DM; k += 4) {
    float4 w = *(const float4*)(wrow + k);
#pragma unroll
    for (int qi = 0; qi < 8; qi++) {
      float4 x = *(const float4*)&ql[qi * DM + k];
      acc[qi] += x.x * w.x + x.y * w.y + x.z * w.z + x.w * w.w;
    }
  }
  const float scale = 0.17677669529663687f;  // 1/sqrt(32)
  int h = d >> 5, hd = d & 31;
#pragma unroll
  for (int qi = 0; qi < 8; qi++) {
    int r = r0 + qi;
    float v = (r < NQ) ? acc[qi] * scale : 0.f;
    Qw[(((size_t)b * NHEAD + h) * QPAD + r) * HDIM + hd] = f2bf(v);
  }
}

// ---------------------------------------------------------------------------
// Kernel 2: KV projection GEMM, LDS-staged 128x128 tile, 4 waves (2x2).
// A: src fp32 -> bf16 fused at staging. B: bf16 weights via global_load_lds
// with XOR k-slot swizzle (slot' = quad ^ ((col>>1)&3)) -> 2-way-free reads.
// K tiles use SWAPPED mfma operands (C^T: reg=hd, lane=token) so the
// epilogue packs 4 regs into one 8B store at consecutive hd; V tiles use
// normal orientation (reg=token, consecutive along V^T rows). Both paths:
// 8B/lane, 32B-contiguous per quad -> full-sector HBM writes.
// ---------------------------------------------------------------------------
__global__ __launch_bounds__(256) void kv_gemm_kernel(
    const float* __restrict__ src, const short* __restrict__ Wkv,
    const float* __restrict__ bk, const float* __restrict__ bv,
    const int* __restrict__ offs, short* __restrict__ Kw,
    short* __restrict__ Vw, int T, int Bn, int Mtiles) {
  int ntile = blockIdx.x / Mtiles;
  int mtile = blockIdx.x % Mtiles;
  int t0 = mtile * BM;
  int n0 = ntile * BN;
  bool isK = (n0 < DM);
  int n0rel = n0 & (DM - 1);
  const float* bias = isK ? bk : bv;

  int tid = threadIdx.x;
  int wave = tid >> 6, lane = tid & 63;
  int l15 = lane & 15, quad = lane >> 4;
  int wm = wave >> 1, wn = wave & 1;

  __shared__ __align__(16) short As[BM][BK + 8];  // padded (80B stride)
  __shared__ __align__(16) short Bs[BN * BK];     // swizzled k-slots

  f32x4 acc[4][4];
#pragma unroll
  for (int i = 0; i < 4; i++)
#pragma unroll
    for (int j = 0; j < 4; j++) acc[i][j] = (f32x4){0.f, 0.f, 0.f, 0.f};

  for (int kk = 0; kk < DM; kk += BK) {
    __syncthreads();
    // ---- stage A: 128 rows x 32 k, fp32 -> bf16 ----
#pragma unroll
    for (int s2 = 0; s2 < 2; s2++) {
      int s = tid + s2 * 256;
      int row = s >> 2, ch = s & 3;
      int tok = t0 + row;
      if (tok >= T) tok = T - 1;
      *(bf16x8*)&As[row][ch * 8] = cvt8(src + (size_t)tok * DM + kk + ch * 8);
    }
    // ---- stage B: 128 cols x 32 k bf16 via global_load_lds, swizzled ----
    {
      int cloc = lane >> 2;  // col within 16-col chunk
#pragma unroll
      for (int j = 0; j < 2; j++) {
        int cb = wave * 32 + j * 16;          // wave-uniform LDS base col
        int c = cb + cloc;                    // tile col this lane fetches
        int slot = (lane & 3) ^ ((c >> 1) & 3);
        const short* g = Wkv + (size_t)(n0 + c) * DM + kk + slot * 8;
        gl2lds16(g, &Bs[cb * BK]);
      }
    }
    __syncthreads();
    // ---- fragments + MFMA ----
    bf16x8 af[4], bf_[4];
#pragma unroll
    for (int mt = 0; mt < 4; mt++)
      af[mt] = *(const bf16x8*)&As[wm * 64 + mt * 16 + l15][quad * 8];
#pragma unroll
    for (int nt = 0; nt < 4; nt++) {
      int c = wn * 64 + nt * 16 + l15;
      int slot = quad ^ ((c >> 1) & 3);
      bf_[nt] = *(const bf16x8*)&Bs[c * BK + slot * 8];
    }
    if (isK) {
#pragma unroll
      for (int mt = 0; mt < 4; mt++)
#pragma unroll
        for (int nt = 0; nt < 4; nt++)
          acc[mt][nt] = __builtin_amdgcn_mfma_f32_16x16x32_bf16(
              bf_[nt], af[mt], acc[mt][nt], 0, 0, 0);  // C^T
    } else {
#pragma unroll
      for (int mt = 0; mt < 4; mt++)
#pragma unroll
        for (int nt = 0; nt < 4; nt++)
          acc[mt][nt] = __builtin_amdgcn_mfma_f32_16x16x32_bf16(
              af[mt], bf_[nt], acc[mt][nt], 0, 0, 0);
    }
  }

  if (isK) {
    // C^T: lane l15 = token (within 16), reg r = hd offset quad*4+r.
    float bk4[4][4];
    int hK[4], hdK[4];
#pragma unroll
    for (int nt = 0; nt < 4; nt++) {
      int nbq = n0rel + wn * 64 + nt * 16 + quad * 4;
      float4 b4 = *(const float4*)(bias + nbq);
      bk4[nt][0] = b4.x; bk4[nt][1] = b4.y; bk4[nt][2] = b4.z; bk4[nt][3] = b4.w;
      hK[nt] = nbq >> 5;
      hdK[nt] = nbq & 31;
    }
    int bcur = 0;
#pragma unroll
    for (int mt = 0; mt < 4; mt++) {
      int tok = t0 + wm * 64 + mt * 16 + l15;
      if (tok >= T) continue;
      while (bcur + 1 < Bn && offs[bcur + 1] <= tok) bcur++;
      int off = offs[bcur], len = offs[bcur + 1] - off;
      int l = tok - off;
      size_t bb = (size_t)off * DM;
#pragma unroll
      for (int nt = 0; nt < 4; nt++) {
        bf16x4 p;
#pragma unroll
        for (int r = 0; r < 4; r++) p[r] = f2bf(acc[mt][nt][r] + bk4[nt][r]);
        *(bf16x4*)&Kw[bb + (size_t)hK[nt] * len * HDIM + (size_t)l * HDIM +
                      hdK[nt]] = p;
      }
    }
  } else {
    // Normal C: lane l15 = hd (within 16), reg r = token offset quad*4+r.
    float bV[4];
    int hV[4], hdV[4];
#pragma unroll
    for (int nt = 0; nt < 4; nt++) {
      int nb = n0rel + wn * 64 + nt * 16 + l15;
      bV[nt] = bias[nb];
      hV[nt] = nb >> 5;
      hdV[nt] = nb & 31;
    }
    int bcur = 0;
#pragma unroll
    for (int mt = 0; mt < 4; mt++) {
      int tb = t0 + wm * 64 + mt * 16 + quad * 4;
      if (tb >= T) continue;
      while (bcur + 1 < Bn && offs[bcur + 1] <= tb) bcur++;
      int off = offs[bcur], len = offs[bcur + 1] - off;
      size_t bb = (size_t)off * DM;
      bool span = (tb + 3 < offs[bcur + 1]) && (tb + 3 < T);
      if (span) {
        int l = tb - off;
#pragma unroll
        for (int nt = 0; nt < 4; nt++) {
          size_t idx =
              bb + (size_t)hV[nt] * len * HDIM + (size_t)hdV[nt] * len + l;
          bf16x4 p;
#pragma unroll
          for (int r = 0; r < 4; r++) p[r] = f2bf(acc[mt][nt][r] + bV[nt]);
          if ((idx & 3) == 0) {
            *(bf16x4*)&Vw[idx] = p;
          } else {
#pragma unroll
            for (int r = 0; r < 4; r++) Vw[idx + r] = p[r];
          }
        }
      } else {
        int bc2 = bcur;
#pragma unroll
        for (int r = 0; r < 4; r++) {
          int tok = tb + r;
          if (tok >= T) continue;
          while (bc2 + 1 < Bn && offs[bc2 + 1] <= tok) bc2++;
          int off2 = offs[bc2], len2 = offs[bc2 + 1] - off2;
          int l = tok - off2;
          size_t bb2 = (size_t)off2 * DM;
#pragma unroll
          for (int nt = 0; nt < 4; nt++)
            Vw[bb2 + (size_t)hV[nt] * len2 * HDIM + (size_t)hdV[nt] * len2 +
               l] = f2bf(acc[mt][nt][r] + bV[nt]);
        }
      }
    }
  }
}

// ---------------------------------------------------------------------------
// Kernel 3: flash attention per (b, h, chunk). 7 waves x 16 query rows.
// Writes unnormalized O (QPAD x 32, bf16) + per-row (m, l) fp32.
// ---------------------------------------------------------------------------
__global__ __launch_bounds__(448) void attn_kernel(
    const short* __restrict__ Qw, const short* __restrict__ Kw,
    const short* __restrict__ Vw, const int* __restrict__ offs,
    short* __restrict__ Ops, float* __restrict__ Ml, int Bn) {
  int c  = blockIdx.x % NCHUNK;
  int bh = blockIdx.x / NCHUNK;
  int h = bh % NHEAD, b = bh / NHEAD;
  int wave = threadIdx.x >> 6, lane = threadIdx.x & 63;
  int l15 = lane & 15, quad = lane >> 4;

  int off = offs[b], len = offs[b + 1] - off;
  int cl = ((len + NCHUNK * 32 - 1) / (NCHUNK * 32)) * 32;
  int kstart = c * cl;
  int kend   = min(kstart + cl, len);

  const short* Kh = Kw + (size_t)off * DM + (size_t)h * len * HDIM;
  const short* Vh = Vw + (size_t)off * DM + (size_t)h * len * HDIM;

  int row16 = wave * 16 + l15;
  bf16x8 aq = *(const bf16x8*)(
      Qw + (((size_t)b * NHEAD + h) * QPAD + row16) * HDIM + quad * 8);

  f32x4 o[2];
#pragma unroll
  for (int j = 0; j < 2; j++) o[j] = (f32x4){0.f, 0.f, 0.f, 0.f};
  float mrun[4], lrun[4];
#pragma unroll
  for (int r = 0; r < 4; r++) { mrun[r] = -1e30f; lrun[r] = 0.f; }

  __shared__ __align__(16) short plds[7][16][40];  // wave-private P transpose

  for (int kb = kstart; kb < kend; kb += 32) {
    bool valid[2];
    bf16x8 bk_[2];
#pragma unroll
    for (int nt = 0; nt < 2; nt++) {
      int key = kb + nt * 16 + l15;
      valid[nt] = key < kend;
      bk_[nt] = valid[nt]
                    ? *(const bf16x8*)(Kh + (size_t)key * HDIM + quad * 8)
                    : bzero8();
    }
    f32x4 zero = {0.f, 0.f, 0.f, 0.f};
    f32x4 s[2];
#pragma unroll
    for (int nt = 0; nt < 2; nt++)
      s[nt] = __builtin_amdgcn_mfma_f32_16x16x32_bf16(aq, bk_[nt], zero, 0, 0, 0);
#pragma unroll
    for (int r = 0; r < 4; r++) {
      float v0 = valid[0] ? s[0][r] : -1e30f;
      float v1 = valid[1] ? s[1][r] : -1e30f;
      float t = fmaxf(v0, v1);
      t = fmaxf(t, __shfl_xor(t, 1, 16));
      t = fmaxf(t, __shfl_xor(t, 2, 16));
      t = fmaxf(t, __shfl_xor(t, 4, 16));
      t = fmaxf(t, __shfl_xor(t, 8, 16));
      float mn = fmaxf(mrun[r], t);
      float al = __expf(mrun[r] - mn);
      float p0 = valid[0] ? __expf(v0 - mn) : 0.f;
      float p1 = valid[1] ? __expf(v1 - mn) : 0.f;
      float rs = p0 + p1;
      rs += __shfl_xor(rs, 1, 16);
      rs += __shfl_xor(rs, 2, 16);
      rs += __shfl_xor(rs, 4, 16);
      rs += __shfl_xor(rs, 8, 16);
      lrun[r] = al * lrun[r] + rs;
      mrun[r] = mn;
      o[0][r] *= al;
      o[1][r] *= al;
      plds[wave][quad * 4 + r][l15]      = f2bf(p0);
      plds[wave][quad * 4 + r][16 + l15] = f2bf(p1);
    }
    bf16x8 pa = *(const bf16x8*)&plds[wave][l15][quad * 8];
    bf16x8 bv_[2];
#pragma unroll
    for (int ht = 0; ht < 2; ht++) {
      int hd = ht * 16 + l15;
      int k0 = kb + quad * 8;
      const short* p = Vh + (size_t)hd * len + k0;
      if (k0 + 7 < len) {
        bv_[ht] = *(const bf16x8*)p;
      } else {
        bf16x8 v;
#pragma unroll
        for (int j = 0; j < 8; j++) v[j] = (k0 + j < len) ? p[j] : (short)0;
        bv_[ht] = v;
      }
    }
#pragma unroll
    for (int ht = 0; ht < 2; ht++)
      o[ht] = __builtin_amdgcn_mfma_f32_16x16x32_bf16(pa, bv_[ht], o[ht], 0, 0, 0);
  }

#pragma unroll
  for (int r = 0; r < 4; r++) {
    int row = wave * 16 + quad * 4 + r;
    size_t base = (((size_t)c * Bn + b) * NHEAD + h) * QPAD + row;
#pragma unroll
    for (int ht = 0; ht < 2; ht++)
      Ops[base * HDIM + ht * 16 + l15] = f2bf(o[ht][r]);
    if (l15 == 0) {
      Ml[base * 2]     = mrun[r];
      Ml[base * 2 + 1] = lrun[r];
    }
  }
}

// ---------------------------------------------------------------------------
// Kernel 4: chunk combine + out-projection + residual.
// ---------------------------------------------------------------------------
__global__ __launch_bounds__(256) void combine_kernel(
    const short* __restrict__ Ops, const float* __restrict__ Ml,
    const float* __restrict__ query, const float* __restrict__ Wo,
    const float* __restrict__ bo, float* __restrict__ out, int Bn, int NQ) {
  int bpb = (NQ + 7) / 8;
  int b  = blockIdx.x / bpb;
  int q0 = (blockIdx.x % bpb) * 8;
  __shared__ __align__(16) float ctx[8 * DM];
  int d = threadIdx.x;
  int h = d >> 5, hd = d & 31;
#pragma unroll
  for (int qi = 0; qi < 8; qi++) {
    int q = q0 + qi;
    float val = 0.f;
    if (q < NQ) {
      float mc[NCHUNK], lc[NCHUNK], M = -1e30f;
#pragma unroll
      for (int c = 0; c < NCHUNK; c++) {
        size_t base = (((size_t)c * Bn + b) * NHEAD + h) * QPAD + q;
        mc[c] = Ml[base * 2];
        lc[c] = Ml[base * 2 + 1];
        M = fmaxf(M, mc[c]);
      }
      float L = 0.f, acc = 0.f;
#pragma unroll
      for (int c = 0; c < NCHUNK; c++) {
        size_t base = (((size_t)c * Bn + b) * NHEAD + h) * QPAD + q;
        float w = __expf(mc[c] - M);
        L += lc[c] * w;
        acc += w * bf2f(Ops[base * HDIM + hd]);
      }
      val = (L > 0.f) ? acc / L : 0.f;
    }
    ctx[qi * DM + d] = val;
  }
  __syncthreads();
  const float* wrow = Wo + (size_t)d * DM;
  float acc[8];
  float bias = bo[d];
#pragma unroll
  for (int qi = 0; qi < 8; qi++) acc[qi] = bias;
  for (int k = 0; k < DM; k += 4) {
    float4 w = *(const float4*)(wrow + k);
#pragma unroll
    for (int qi = 0; qi < 8; qi++) {
      float4 x = *(const float4*)&ctx[qi * DM + k];
      acc[qi] += x.x * w.x + x.y * w.y + x.z * w.z + x.w * w.w;
    }
  }
#pragma unroll
  for (int qi = 0; qi < 8; qi++) {
    int q = q0 + qi;
    if (q < NQ)
      out[((size_t)b * NQ + q) * DM + d] =
          acc[qi] + query[((size_t)b * NQ + q) * DM + d];
  }
}

// ---------------------------------------------------------------------------
extern "C" void kernel_launch(void* const* d_in, const int* in_sizes, int n_in,
                              void* d_out, int out_size, void* d_ws,
                              size_t ws_size, hipStream_t stream) {
  const float* src   = (const float*)d_in[0];
  const float* query = (const float*)d_in[1];
  const int*   offs  = (const int*)d_in[2];
  const float* Wq = (const float*)d_in[3];
  const float* bq = (const float*)d_in[4];
  const float* Wk = (const float*)d_in[5];
  const float* bk = (const float*)d_in[6];
  const float* Wv = (const float*)d_in[7];
  const float* bv = (const float*)d_in[8];
  const float* Wo = (const float*)d_in[9];
  const float* bo = (const float*)d_in[10];
  float* out = (float*)d_out;

  int T  = in_sizes[0] / DM;        // total tokens (65536)
  int Bn = in_sizes[2] - 1;         // batch size (16)
  int NQ = in_sizes[1] / (Bn * DM); // queries per sample (100)

  // Workspace layout (~77 MB):
  char* w = (char*)d_ws;
  size_t qsz = (size_t)Bn * NHEAD * QPAD * HDIM * 2;            // 0.92 MB
  size_t ksz = (size_t)T * DM * 2;                              // 33.5 MB
  size_t osz = (size_t)NCHUNK * Bn * NHEAD * QPAD * HDIM * 2;   // 7.3 MB (bf16)
  size_t msz = (size_t)NCHUNK * Bn * NHEAD * QPAD * 2 * 4;      // 0.92 MB
  short* Qw  = (short*)w;
  short* Kw  = (short*)(w + qsz);
  short* Vw  = (short*)(w + qsz + ksz);
  short* Ops = (short*)(w + qsz + 2 * ksz);
  float* Mlp = (float*)(w + qsz + 2 * ksz + osz);
  short* Wkv = (short*)(w + qsz + 2 * ksz + osz + msz);         // 0.26 MB

  int Mtiles = (T + BM - 1) / BM;

  wconv_kernel<<<(2 * DM * DM) / (256 * 8), 256, 0, stream>>>(Wk, Wv, Wkv);
  q_proj_kernel<<<Bn * (QPAD / 8), 256, 0, stream>>>(query, Wq, bq, Qw, Bn, NQ);
  kv_gemm_kernel<<<Mtiles * (2 * DM / BN), 256, 0, stream>>>(
      src, Wkv, bk, bv, offs, Kw, Vw, T, Bn, Mtiles);
  attn_kernel<<<Bn * NHEAD * NCHUNK, 448, 0, stream>>>(Qw, Kw, Vw, offs, Ops,
                                                       Mlp, Bn);
  combine_kernel<<<Bn * ((NQ + 7) / 8), 256, 0, stream>>>(Ops, Mlp, query, Wo,
                                                          bo, out, Bn, NQ);
}